// Round 1
// baseline (300.420 us; speedup 1.0000x reference)
//
#include <hip/hip_runtime.h>

#define DMODEL 512
#define EPS_IN 1e-4f
#define EPS_LN 1e-5f
#define CLIPV  5.0f

struct TypeParams {
    const float* x;
    const float* mean;
    const float* var;
    const float* W;
    const float* b;
    const float* gamma;
    const float* beta;
    int n;        // rows of this type
    int offset;   // row offset in concat order
    int nb;       // number of blocks for this type
};

// Build inverse permutation + write tbatch/etype outputs.
// out[j] = x_concat[index_map[j]]  =>  row r of concat goes to out row inv[r].
__global__ __launch_bounds__(256) void setup_kernel(
    const int* __restrict__ index_map, const int* __restrict__ batch_index,
    int* __restrict__ inv, float* __restrict__ out_t, float* __restrict__ out_e,
    int total, int n0, int n01)
{
    const int j = blockIdx.x * 256 + threadIdx.x;
    if (j >= total) return;
    const int r = index_map[j];
    inv[r] = j;
    out_t[j] = (float)batch_index[r];
    out_e[j] = (r < n0) ? 0.0f : ((r < n01) ? 1.0f : 2.0f);
}

// One wave handles 8 rows; lane owns 8 contiguous output columns.
template<int F>
__device__ __forceinline__ void embed_body(
    const TypeParams& p, int bid, const int* __restrict__ inv,
    float* __restrict__ out, float* xs)
{
    const int lane = threadIdx.x & 63;
    const int wv   = threadIdx.x >> 6;
    const int rowbase = bid * 32 + wv * 8;

    // ---- InputNorm: stage 8 normalized rows into LDS (wave-private region)
    float* xw = xs + wv * (8 * F);
    for (int idx = lane; idx < 8 * F; idx += 64) {
        const int r = idx / F;           // F is compile-time const
        const int c = idx - r * F;
        const int row = rowbase + r;
        float v = 0.0f;
        if (row < p.n) {
            v = p.x[(size_t)row * F + c];
            v = (v - p.mean[c]) * rsqrtf(p.var[c] + EPS_IN);
            v = fminf(fmaxf(v, -CLIPV), CLIPV);
        }
        xw[idx] = v;
    }
    __syncthreads();

    const int col = lane * 8;

    float acc[8][8];
#pragma unroll
    for (int r = 0; r < 8; ++r)
#pragma unroll
        for (int c = 0; c < 8; ++c) acc[r][c] = 0.0f;

    // ---- GEMM: h[r][col..col+7] = sum_k xn[r][k] * W[k][col..col+7]
    const float* wp = p.W + col;
#pragma unroll 2
    for (int k = 0; k < F; ++k) {
        const float4 w0 = *(const float4*)(wp + (size_t)k * DMODEL);
        const float4 w1 = *(const float4*)(wp + (size_t)k * DMODEL + 4);
#pragma unroll
        for (int r = 0; r < 8; ++r) {
            const float s = xw[r * F + k];   // LDS broadcast
            acc[r][0] = fmaf(s, w0.x, acc[r][0]);
            acc[r][1] = fmaf(s, w0.y, acc[r][1]);
            acc[r][2] = fmaf(s, w0.z, acc[r][2]);
            acc[r][3] = fmaf(s, w0.w, acc[r][3]);
            acc[r][4] = fmaf(s, w1.x, acc[r][4]);
            acc[r][5] = fmaf(s, w1.y, acc[r][5]);
            acc[r][6] = fmaf(s, w1.z, acc[r][6]);
            acc[r][7] = fmaf(s, w1.w, acc[r][7]);
        }
    }

    // ---- epilogue: +bias, ReLU, LayerNorm (wave-wide), scatter row to out
    const float4 bb0 = *(const float4*)(p.b + col);
    const float4 bb1 = *(const float4*)(p.b + col + 4);
    const float4 gg0 = *(const float4*)(p.gamma + col);
    const float4 gg1 = *(const float4*)(p.gamma + col + 4);
    const float4 ee0 = *(const float4*)(p.beta + col);
    const float4 ee1 = *(const float4*)(p.beta + col + 4);
    const float bv[8] = {bb0.x, bb0.y, bb0.z, bb0.w, bb1.x, bb1.y, bb1.z, bb1.w};
    const float gv[8] = {gg0.x, gg0.y, gg0.z, gg0.w, gg1.x, gg1.y, gg1.z, gg1.w};
    const float ev[8] = {ee0.x, ee0.y, ee0.z, ee0.w, ee1.x, ee1.y, ee1.z, ee1.w};

#pragma unroll
    for (int r = 0; r < 8; ++r) {
        float v[8];
        float sum = 0.0f, sq = 0.0f;
#pragma unroll
        for (int c = 0; c < 8; ++c) {
            v[c] = fmaxf(acc[r][c] + bv[c], 0.0f);
            sum += v[c];
            sq   = fmaf(v[c], v[c], sq);
        }
#pragma unroll
        for (int off = 32; off > 0; off >>= 1) {
            sum += __shfl_xor(sum, off, 64);
            sq  += __shfl_xor(sq,  off, 64);
        }
        const float mu = sum * (1.0f / DMODEL);
        const float vr = fmaxf(sq * (1.0f / DMODEL) - mu * mu, 0.0f);
        const float sc = rsqrtf(vr + EPS_LN);

        const int row = rowbase + r;
        if (row < p.n) {
            const int orow = inv[p.offset + row];
            float4 o0, o1;
            o0.x = fmaf(gv[0] * sc, v[0] - mu, ev[0]);
            o0.y = fmaf(gv[1] * sc, v[1] - mu, ev[1]);
            o0.z = fmaf(gv[2] * sc, v[2] - mu, ev[2]);
            o0.w = fmaf(gv[3] * sc, v[3] - mu, ev[3]);
            o1.x = fmaf(gv[4] * sc, v[4] - mu, ev[4]);
            o1.y = fmaf(gv[5] * sc, v[5] - mu, ev[5]);
            o1.z = fmaf(gv[6] * sc, v[6] - mu, ev[6]);
            o1.w = fmaf(gv[7] * sc, v[7] - mu, ev[7]);
            float* op = out + (size_t)orow * DMODEL + col;
            *(float4*)(op)     = o0;
            *(float4*)(op + 4) = o1;
        }
    }
}

__global__ __launch_bounds__(256) void embed_all(
    TypeParams p0, TypeParams p1, TypeParams p2,
    const int* __restrict__ inv, float* __restrict__ out)
{
    extern __shared__ float xs[];
    const int bid = blockIdx.x;
    if (bid < p0.nb) {
        embed_body<64>(p0, bid, inv, out, xs);
    } else if (bid < p0.nb + p1.nb) {
        embed_body<128>(p1, bid - p0.nb, inv, out, xs);
    } else {
        embed_body<48>(p2, bid - p0.nb - p1.nb, inv, out, xs);
    }
}

extern "C" void kernel_launch(void* const* d_in, const int* in_sizes, int n_in,
                              void* d_out, int out_size, void* d_ws, size_t ws_size,
                              hipStream_t stream)
{
    const int F0 = 64, F1 = 128, F2 = 48;
    const int n0 = in_sizes[0]  / F0;
    const int n1 = in_sizes[7]  / F1;
    const int n2 = in_sizes[14] / F2;
    const int total = n0 + n1 + n2;

    float* out   = (float*)d_out;
    float* out_t = out + (size_t)total * DMODEL;
    float* out_e = out_t + total;
    int*   inv   = (int*)d_ws;

    const int* index_map   = (const int*)d_in[21];
    const int* batch_index = (const int*)d_in[22];

    setup_kernel<<<(total + 255) / 256, 256, 0, stream>>>(
        index_map, batch_index, inv, out_t, out_e, total, n0, n0 + n1);

    TypeParams p0{(const float*)d_in[0],  (const float*)d_in[1],  (const float*)d_in[2],
                  (const float*)d_in[3],  (const float*)d_in[4],  (const float*)d_in[5],
                  (const float*)d_in[6],  n0, 0,        (n0 + 31) / 32};
    TypeParams p1{(const float*)d_in[7],  (const float*)d_in[8],  (const float*)d_in[9],
                  (const float*)d_in[10], (const float*)d_in[11], (const float*)d_in[12],
                  (const float*)d_in[13], n1, n0,       (n1 + 31) / 32};
    TypeParams p2{(const float*)d_in[14], (const float*)d_in[15], (const float*)d_in[16],
                  (const float*)d_in[17], (const float*)d_in[18], (const float*)d_in[19],
                  (const float*)d_in[20], n2, n0 + n1,  (n2 + 31) / 32};

    const int nb = p0.nb + p1.nb + p2.nb;
    embed_all<<<nb, 256, 32 * 128 * sizeof(float), stream>>>(p0, p1, p2, inv, out);
}

// Round 2
// 191.680 us; speedup vs baseline: 1.5673x; 1.5673x over previous
//
#include <hip/hip_runtime.h>

#define DMODEL 512
#define EPS_IN 1e-4f
#define EPS_LN 1e-5f
#define CLIPV  5.0f

typedef float f32x4 __attribute__((ext_vector_type(4)));
typedef short s16x8 __attribute__((ext_vector_type(8)));

__device__ __forceinline__ unsigned short f2bf(float f) {
    union { float f; unsigned u; } v; v.f = f;
    unsigned r = v.u + 0x7fffu + ((v.u >> 16) & 1u);
    return (unsigned short)(r >> 16);
}

struct TypeParams {
    const float* x; const float* mean; const float* var;
    const unsigned short* Wt;          // [512][Kp] bf16, zero-padded K
    const float* b; const float* gamma; const float* beta;
    int n;        // rows of this type
    int offset;   // row offset in concat order
    int nb;       // blocks (64 rows each)
};

// inv permutation + tbatch/etype outputs
__global__ __launch_bounds__(256) void setup_kernel(
    const int* __restrict__ index_map, const int* __restrict__ batch_index,
    int* __restrict__ inv, float* __restrict__ out_t, float* __restrict__ out_e,
    int total, int n0, int n01)
{
    const int j = blockIdx.x * 256 + threadIdx.x;
    if (j >= total) return;
    const int r = index_map[j];
    inv[r] = j;
    out_t[j] = (float)batch_index[r];
    out_e[j] = (r < n0) ? 0.0f : ((r < n01) ? 1.0f : 2.0f);
}

// W [K][512] f32  ->  Wt [512][Kp] bf16 (transposed, zero-padded)
__global__ __launch_bounds__(256) void prep_w(
    const float* __restrict__ W0, const float* __restrict__ W1, const float* __restrict__ W2,
    unsigned short* __restrict__ Wt0, unsigned short* __restrict__ Wt1, unsigned short* __restrict__ Wt2)
{
    int idx = blockIdx.x * 256 + threadIdx.x;
    const float* W; unsigned short* Wt; int K, Kp;
    if (idx < DMODEL * 64)              { W = W0; Wt = Wt0; K = 64;  Kp = 64; }
    else if (idx < DMODEL * (64 + 128)) { idx -= DMODEL * 64;  W = W1; Wt = Wt1; K = 128; Kp = 128; }
    else if (idx < DMODEL * 256)        { idx -= DMODEL * 192; W = W2; Wt = Wt2; K = 48;  Kp = 64; }
    else return;
    const int nn = idx / Kp, k = idx - nn * Kp;
    const float w = (k < K) ? W[(size_t)k * DMODEL + nn] : 0.0f;
    Wt[idx] = f2bf(w);
}

// Block: 64 rows x 512 cols. 8 waves = 2(M) x 4(N). Wave: 32 rows x 128 cols.
template<int F, int KP>
__device__ __forceinline__ void embed_body(
    const TypeParams& p, int bid, const int* __restrict__ inv,
    float* __restrict__ out, char* lds)
{
    const int tid  = threadIdx.x;
    const int lane = tid & 63;
    const int w    = tid >> 6;     // 0..7
    const int wm   = w >> 2;       // 0..1
    const int wn   = w & 3;        // 0..3
    const int l15  = lane & 15;
    const int g    = lane >> 4;    // 0..3
    const int row0 = bid * 64;
    const int n    = p.n;

    // ---- stage: InputNorm(x) -> bf16 LDS tile [64][KP], 16B-slot XOR swizzle
    constexpr int SEG = KP / 8;
    for (int idx = tid; idx < 64 * SEG; idx += 512) {
        const int r = idx / SEG;
        const int s = idx - r * SEG;
        const int c = s * 8;
        const int gr = row0 + r;
        s16x8 pk;
        if (gr < n && c < F) {
            const float4 x0 = *(const float4*)(p.x + (size_t)gr * F + c);
            const float4 x1 = *(const float4*)(p.x + (size_t)gr * F + c + 4);
            const float4 m0 = *(const float4*)(p.mean + c);
            const float4 m1 = *(const float4*)(p.mean + c + 4);
            const float4 v0 = *(const float4*)(p.var + c);
            const float4 v1 = *(const float4*)(p.var + c + 4);
            float t[8] = {x0.x - m0.x, x0.y - m0.y, x0.z - m0.z, x0.w - m0.w,
                          x1.x - m1.x, x1.y - m1.y, x1.z - m1.z, x1.w - m1.w};
            const float iv[8] = {rsqrtf(v0.x + EPS_IN), rsqrtf(v0.y + EPS_IN),
                                 rsqrtf(v0.z + EPS_IN), rsqrtf(v0.w + EPS_IN),
                                 rsqrtf(v1.x + EPS_IN), rsqrtf(v1.y + EPS_IN),
                                 rsqrtf(v1.z + EPS_IN), rsqrtf(v1.w + EPS_IN)};
#pragma unroll
            for (int jj = 0; jj < 8; ++jj)
                pk[jj] = (short)f2bf(fminf(fmaxf(t[jj] * iv[jj], -CLIPV), CLIPV));
        } else {
#pragma unroll
            for (int jj = 0; jj < 8; ++jj) pk[jj] = 0;
        }
        int byte = r * (KP * 2) + s * 16;
        byte ^= (r & 7) << 4;
        *reinterpret_cast<s16x8*>(lds + byte) = pk;
    }
    __syncthreads();

    // ---- MFMA: acc[m][t] = 16x16 tile, rows wm*32+m*16+.., cols wn*128+t*16+..
    f32x4 acc[2][8];
#pragma unroll
    for (int m = 0; m < 2; ++m)
#pragma unroll
        for (int t = 0; t < 8; ++t) acc[m][t] = (f32x4)0.0f;

    const int arow = wm * 32 + l15;
    const unsigned short* wtl = p.Wt + (size_t)(wn * 128 + l15) * KP + g * 8;

#pragma unroll
    for (int ks = 0; ks < KP / 32; ++ks) {
        const int kb = ks * 64 + g * 16;
        int a0b = arow * (KP * 2) + kb;        a0b ^= (arow & 7) << 4;
        int a1b = (arow + 16) * (KP * 2) + kb; a1b ^= (arow & 7) << 4;  // (r+16)&7==r&7
        const s16x8 a0 = *reinterpret_cast<const s16x8*>(lds + a0b);
        const s16x8 a1 = *reinterpret_cast<const s16x8*>(lds + a1b);
#pragma unroll
        for (int t = 0; t < 8; ++t) {
            const s16x8 bf = *reinterpret_cast<const s16x8*>(wtl + (size_t)t * 16 * KP + ks * 32);
            acc[0][t] = __builtin_amdgcn_mfma_f32_16x16x32_bf16(a0, bf, acc[0][t], 0, 0, 0);
            acc[1][t] = __builtin_amdgcn_mfma_f32_16x16x32_bf16(a1, bf, acc[1][t], 0, 0, 0);
        }
    }

    // ---- epilogue: bias+ReLU, LayerNorm (16-lane shfl + cross-wave LDS), scatter
    float bv[8], gv[8], ev[8];
#pragma unroll
    for (int t = 0; t < 8; ++t) {
        const int col = wn * 128 + t * 16 + l15;
        bv[t] = p.b[col]; gv[t] = p.gamma[col]; ev[t] = p.beta[col];
    }

    float ps[2][4] = {{0}}, pq[2][4] = {{0}};
#pragma unroll
    for (int m = 0; m < 2; ++m)
#pragma unroll
        for (int t = 0; t < 8; ++t)
#pragma unroll
            for (int j = 0; j < 4; ++j) {
                const float v = fmaxf(acc[m][t][j] + bv[t], 0.0f);
                ps[m][j] += v;
                pq[m][j] = fmaf(v, v, pq[m][j]);
            }
#pragma unroll
    for (int off = 1; off < 16; off <<= 1)
#pragma unroll
        for (int m = 0; m < 2; ++m)
#pragma unroll
            for (int j = 0; j < 4; ++j) {
                ps[m][j] += __shfl_xor(ps[m][j], off, 64);
                pq[m][j] += __shfl_xor(pq[m][j], off, 64);
            }

    float2* red = reinterpret_cast<float2*>(lds + 64 * KP * 2);  // [64 rows][4 wn]
    if (l15 == 0) {
#pragma unroll
        for (int m = 0; m < 2; ++m)
#pragma unroll
            for (int j = 0; j < 4; ++j) {
                const int rl = wm * 32 + m * 16 + 4 * g + j;
                red[rl * 4 + wn] = make_float2(ps[m][j], pq[m][j]);
            }
    }
    __syncthreads();

    float mu[2][4], sc[2][4]; int orow[2][4]; bool okr[2][4];
#pragma unroll
    for (int m = 0; m < 2; ++m)
#pragma unroll
        for (int j = 0; j < 4; ++j) {
            const int rl = wm * 32 + m * 16 + 4 * g + j;
            float s = 0.0f, q = 0.0f;
#pragma unroll
            for (int wq = 0; wq < 4; ++wq) { const float2 e = red[rl * 4 + wq]; s += e.x; q += e.y; }
            const float mmu = s * (1.0f / DMODEL);
            const float vv  = fmaxf(q * (1.0f / DMODEL) - mmu * mmu, 0.0f);
            mu[m][j] = mmu;
            sc[m][j] = rsqrtf(vv + EPS_LN);
            const int rg = row0 + rl;
            okr[m][j] = (rg < n);
            orow[m][j] = okr[m][j] ? inv[p.offset + rg] : 0;
        }

#pragma unroll
    for (int m = 0; m < 2; ++m)
#pragma unroll
        for (int j = 0; j < 4; ++j) {
            if (!okr[m][j]) continue;
            float* op = out + (size_t)orow[m][j] * DMODEL + wn * 128 + l15;
            const float mmu = mu[m][j], ssc = sc[m][j];
#pragma unroll
            for (int t = 0; t < 8; ++t) {
                const float v = fmaxf(acc[m][t][j] + bv[t], 0.0f);
                op[t * 16] = fmaf(gv[t] * ssc, v - mmu, ev[t]);
            }
        }
}

__global__ __launch_bounds__(512) void embed_all(
    TypeParams p0, TypeParams p1, TypeParams p2,
    const int* __restrict__ inv, float* __restrict__ out)
{
    extern __shared__ char lds[];
    const int bid = blockIdx.x;
    if (bid < p0.nb)                embed_body<64, 64>  (p0, bid, inv, out, lds);
    else if (bid < p0.nb + p1.nb)   embed_body<128, 128>(p1, bid - p0.nb, inv, out, lds);
    else                            embed_body<48, 64>  (p2, bid - p0.nb - p1.nb, inv, out, lds);
}

extern "C" void kernel_launch(void* const* d_in, const int* in_sizes, int n_in,
                              void* d_out, int out_size, void* d_ws, size_t ws_size,
                              hipStream_t stream)
{
    const int F0 = 64, F1 = 128, F2 = 48;
    const int n0 = in_sizes[0]  / F0;
    const int n1 = in_sizes[7]  / F1;
    const int n2 = in_sizes[14] / F2;
    const int total = n0 + n1 + n2;

    float* out   = (float*)d_out;
    float* out_t = out + (size_t)total * DMODEL;
    float* out_e = out_t + total;

    // ws layout: inv[total] ints, then Wt0/Wt1/Wt2 bf16
    int* inv = (int*)d_ws;
    unsigned short* Wt0 = (unsigned short*)((char*)d_ws + ((size_t)total * 4 + 255 & ~(size_t)255));
    unsigned short* Wt1 = Wt0 + DMODEL * 64;
    unsigned short* Wt2 = Wt1 + DMODEL * 128;

    const int* index_map   = (const int*)d_in[21];
    const int* batch_index = (const int*)d_in[22];

    setup_kernel<<<(total + 255) / 256, 256, 0, stream>>>(
        index_map, batch_index, inv, out_t, out_e, total, n0, n0 + n1);

    prep_w<<<(DMODEL * 256 + 255) / 256, 256, 0, stream>>>(
        (const float*)d_in[3], (const float*)d_in[10], (const float*)d_in[17],
        Wt0, Wt1, Wt2);

    TypeParams p0{(const float*)d_in[0],  (const float*)d_in[1],  (const float*)d_in[2],
                  Wt0, (const float*)d_in[4],  (const float*)d_in[5],  (const float*)d_in[6],
                  n0, 0,       (n0 + 63) / 64};
    TypeParams p1{(const float*)d_in[7],  (const float*)d_in[8],  (const float*)d_in[9],
                  Wt1, (const float*)d_in[11], (const float*)d_in[12], (const float*)d_in[13],
                  n1, n0,      (n1 + 63) / 64};
    TypeParams p2{(const float*)d_in[14], (const float*)d_in[15], (const float*)d_in[16],
                  Wt2, (const float*)d_in[18], (const float*)d_in[19], (const float*)d_in[20],
                  n2, n0 + n1, (n2 + 63) / 64};

    const int nb = p0.nb + p1.nb + p2.nb;
    const int lds_size = 64 * 128 * 2 + 64 * 4 * sizeof(float2);  // 18432 B
    embed_all<<<nb, 512, lds_size, stream>>>(p0, p1, p2, inv, out);
}

// Round 3
// 162.120 us; speedup vs baseline: 1.8531x; 1.1823x over previous
//
#include <hip/hip_runtime.h>

#define DMODEL 512
#define EPS_IN 1e-4f
#define EPS_LN 1e-5f
#define CLIPV  5.0f

typedef float f32x4 __attribute__((ext_vector_type(4)));
typedef short s16x8 __attribute__((ext_vector_type(8)));

__device__ __forceinline__ unsigned short f2bf(float f) {
    union { float f; unsigned u; } v; v.f = f;
    unsigned r = v.u + 0x7fffu + ((v.u >> 16) & 1u);
    return (unsigned short)(r >> 16);
}

struct TypeParams {
    const float* x; const float* mean; const float* var;
    const unsigned short* Wt;          // [512][Kp] bf16, zero-padded K
    const float* b; const float* gamma; const float* beta;
    int n;        // rows of this type
    int offset;   // row offset in concat order
    int nb;       // blocks (32 rows each)
};

// One launch: [part A] inv permutation + tbatch/etype, [part B] W -> Wt bf16 transpose
__global__ __launch_bounds__(256) void setup_all(
    const int* __restrict__ index_map, const int* __restrict__ batch_index,
    int* __restrict__ inv, float* __restrict__ out_t, float* __restrict__ out_e,
    int total, int n0, int n01, int nbA,
    const float* __restrict__ W0, const float* __restrict__ W1, const float* __restrict__ W2,
    unsigned short* __restrict__ Wt0, unsigned short* __restrict__ Wt1, unsigned short* __restrict__ Wt2)
{
    if (blockIdx.x < (unsigned)nbA) {
        const int j = blockIdx.x * 256 + threadIdx.x;
        if (j >= total) return;
        const int r = index_map[j];
        inv[r] = j;
        out_t[j] = (float)batch_index[r];
        out_e[j] = (r < n0) ? 0.0f : ((r < n01) ? 1.0f : 2.0f);
    } else {
        int idx = (blockIdx.x - nbA) * 256 + threadIdx.x;
        const float* W; unsigned short* Wt; int K, Kp;
        if (idx < DMODEL * 64)              { W = W0; Wt = Wt0; K = 64;  Kp = 64; }
        else if (idx < DMODEL * (64 + 128)) { idx -= DMODEL * 64;  W = W1; Wt = Wt1; K = 128; Kp = 128; }
        else if (idx < DMODEL * 256)        { idx -= DMODEL * 192; W = W2; Wt = Wt2; K = 48;  Kp = 64; }
        else return;
        const int nn = idx / Kp, k = idx - nn * Kp;
        const float w = (k < K) ? W[(size_t)k * DMODEL + nn] : 0.0f;
        Wt[idx] = f2bf(w);
    }
}

// Block: 32 rows x 512 cols, 4 waves (1M x 4N). Wave tile: 32 rows x 128 cols.
template<int F, int KP>
__device__ __forceinline__ void embed_body(
    const TypeParams& p, int bid, const int* __restrict__ inv,
    float* __restrict__ out, char* lds)
{
    const int tid  = threadIdx.x;
    const int lane = tid & 63;
    const int wn   = tid >> 6;     // 0..3 (N split)
    const int l15  = lane & 15;
    const int g    = lane >> 4;    // 0..3
    const int row0 = bid * 32;
    const int n    = p.n;

    // ---- stage: InputNorm(x) -> bf16 LDS tile [32][KP], 16B-slot XOR swizzle
    constexpr int SEG = KP / 8;
#pragma unroll
    for (int idx = tid; idx < 32 * SEG; idx += 256) {
        const int r = idx / SEG;
        const int s = idx - r * SEG;
        const int c = s * 8;
        const int gr = row0 + r;
        s16x8 pk;
        if (gr < n && c < F) {
            const float4 x0 = *(const float4*)(p.x + (size_t)gr * F + c);
            const float4 x1 = *(const float4*)(p.x + (size_t)gr * F + c + 4);
            const float4 m0 = *(const float4*)(p.mean + c);
            const float4 m1 = *(const float4*)(p.mean + c + 4);
            const float4 v0 = *(const float4*)(p.var + c);
            const float4 v1 = *(const float4*)(p.var + c + 4);
            const float t[8] = {x0.x - m0.x, x0.y - m0.y, x0.z - m0.z, x0.w - m0.w,
                                x1.x - m1.x, x1.y - m1.y, x1.z - m1.z, x1.w - m1.w};
            const float iv[8] = {rsqrtf(v0.x + EPS_IN), rsqrtf(v0.y + EPS_IN),
                                 rsqrtf(v0.z + EPS_IN), rsqrtf(v0.w + EPS_IN),
                                 rsqrtf(v1.x + EPS_IN), rsqrtf(v1.y + EPS_IN),
                                 rsqrtf(v1.z + EPS_IN), rsqrtf(v1.w + EPS_IN)};
#pragma unroll
            for (int jj = 0; jj < 8; ++jj)
                pk[jj] = (short)f2bf(fminf(fmaxf(t[jj] * iv[jj], -CLIPV), CLIPV));
        } else {
#pragma unroll
            for (int jj = 0; jj < 8; ++jj) pk[jj] = 0;
        }
        int byte = r * (KP * 2) + s * 16;
        byte ^= (r & 7) << 4;
        *reinterpret_cast<s16x8*>(lds + byte) = pk;
    }
    __syncthreads();

    // ---- MFMA: acc[m][t] = 16x16 tile; rows m*16+(4g+j), cols wn*128+t*16+l15
    f32x4 acc[2][8];
#pragma unroll
    for (int m = 0; m < 2; ++m)
#pragma unroll
        for (int t = 0; t < 8; ++t) acc[m][t] = (f32x4)0.0f;

    const unsigned short* wtl = p.Wt + (size_t)(wn * 128 + l15) * KP + g * 8;

#pragma unroll
    for (int ks = 0; ks < KP / 32; ++ks) {
        const int kb = ks * 64 + g * 16;
        int a0b = l15 * (KP * 2) + kb;        a0b ^= (l15 & 7) << 4;
        int a1b = (l15 + 16) * (KP * 2) + kb; a1b ^= (l15 & 7) << 4;  // (r+16)&7==r&7
        const s16x8 a0 = *reinterpret_cast<const s16x8*>(lds + a0b);
        const s16x8 a1 = *reinterpret_cast<const s16x8*>(lds + a1b);
#pragma unroll
        for (int t = 0; t < 8; ++t) {
            const s16x8 bf = *reinterpret_cast<const s16x8*>(wtl + (size_t)t * 16 * KP + ks * 32);
            acc[0][t] = __builtin_amdgcn_mfma_f32_16x16x32_bf16(a0, bf, acc[0][t], 0, 0, 0);
            acc[1][t] = __builtin_amdgcn_mfma_f32_16x16x32_bf16(a1, bf, acc[1][t], 0, 0, 0);
        }
    }

    // ---- epilogue: bias+ReLU, LayerNorm partials (16-lane shfl + cross-wave LDS)
    float bv[8], gv[8], ev[8];
#pragma unroll
    for (int t = 0; t < 8; ++t) {
        const int col = wn * 128 + t * 16 + l15;
        bv[t] = p.b[col]; gv[t] = p.gamma[col]; ev[t] = p.beta[col];
    }

    {
        float ps[2][4] = {{0}}, pq[2][4] = {{0}};
#pragma unroll
        for (int m = 0; m < 2; ++m)
#pragma unroll
            for (int t = 0; t < 8; ++t)
#pragma unroll
                for (int j = 0; j < 4; ++j) {
                    const float v = fmaxf(acc[m][t][j] + bv[t], 0.0f);
                    ps[m][j] += v;
                    pq[m][j] = fmaf(v, v, pq[m][j]);
                }
#pragma unroll
        for (int off = 1; off < 16; off <<= 1)
#pragma unroll
            for (int m = 0; m < 2; ++m)
#pragma unroll
                for (int j = 0; j < 4; ++j) {
                    ps[m][j] += __shfl_xor(ps[m][j], off, 64);
                    pq[m][j] += __shfl_xor(pq[m][j], off, 64);
                }

        float2* red = reinterpret_cast<float2*>(lds + 32 * KP * 2);  // [32 rows][4 wn]
        if (l15 == 0) {
#pragma unroll
            for (int m = 0; m < 2; ++m)
#pragma unroll
                for (int j = 0; j < 4; ++j) {
                    const int rl = m * 16 + 4 * g + j;
                    red[rl * 4 + wn] = make_float2(ps[m][j], pq[m][j]);
                }
        }
    }
    __syncthreads();

    const float2* red = reinterpret_cast<const float2*>(lds + 32 * KP * 2);

    // ---- finish LN + scatter, computed inline per (m,j) to keep VGPR low
#pragma unroll
    for (int m = 0; m < 2; ++m)
#pragma unroll
        for (int j = 0; j < 4; ++j) {
            const int rl = m * 16 + 4 * g + j;
            const int rg = row0 + rl;
            if (rg >= n) continue;
            float s = 0.0f, q = 0.0f;
#pragma unroll
            for (int wq = 0; wq < 4; ++wq) { const float2 e = red[rl * 4 + wq]; s += e.x; q += e.y; }
            const float mu = s * (1.0f / DMODEL);
            const float vv = fmaxf(q * (1.0f / DMODEL) - mu * mu, 0.0f);
            const float sc = rsqrtf(vv + EPS_LN);
            const int orow = inv[p.offset + rg];
            float* op = out + (size_t)orow * DMODEL + wn * 128 + l15;
#pragma unroll
            for (int t = 0; t < 8; ++t) {
                const float v = fmaxf(acc[m][t][j] + bv[t], 0.0f);
                op[t * 16] = fmaf(gv[t] * sc, v - mu, ev[t]);
            }
        }
}

__global__ __launch_bounds__(256, 4) void embed_all(
    TypeParams p0, TypeParams p1, TypeParams p2,
    const int* __restrict__ inv, float* __restrict__ out)
{
    extern __shared__ char lds[];
    const int bid = blockIdx.x;
    if (bid < p0.nb)                embed_body<64, 64>  (p0, bid, inv, out, lds);
    else if (bid < p0.nb + p1.nb)   embed_body<128, 128>(p1, bid - p0.nb, inv, out, lds);
    else                            embed_body<48, 64>  (p2, bid - p0.nb - p1.nb, inv, out, lds);
}

extern "C" void kernel_launch(void* const* d_in, const int* in_sizes, int n_in,
                              void* d_out, int out_size, void* d_ws, size_t ws_size,
                              hipStream_t stream)
{
    const int F0 = 64, F1 = 128, F2 = 48;
    const int n0 = in_sizes[0]  / F0;
    const int n1 = in_sizes[7]  / F1;
    const int n2 = in_sizes[14] / F2;
    const int total = n0 + n1 + n2;

    float* out   = (float*)d_out;
    float* out_t = out + (size_t)total * DMODEL;
    float* out_e = out_t + total;

    // ws layout: inv[total] ints, then Wt0/Wt1/Wt2 bf16
    int* inv = (int*)d_ws;
    unsigned short* Wt0 = (unsigned short*)((char*)d_ws + (((size_t)total * 4 + 255) & ~(size_t)255));
    unsigned short* Wt1 = Wt0 + DMODEL * 64;
    unsigned short* Wt2 = Wt1 + DMODEL * 128;

    const int* index_map   = (const int*)d_in[21];
    const int* batch_index = (const int*)d_in[22];

    const int nbA = (total + 255) / 256;
    const int nbB = (DMODEL * 256 + 255) / 256;
    setup_all<<<nbA + nbB, 256, 0, stream>>>(
        index_map, batch_index, inv, out_t, out_e, total, n0, n0 + n1, nbA,
        (const float*)d_in[3], (const float*)d_in[10], (const float*)d_in[17],
        Wt0, Wt1, Wt2);

    TypeParams p0{(const float*)d_in[0],  (const float*)d_in[1],  (const float*)d_in[2],
                  Wt0, (const float*)d_in[4],  (const float*)d_in[5],  (const float*)d_in[6],
                  n0, 0,       (n0 + 31) / 32};
    TypeParams p1{(const float*)d_in[7],  (const float*)d_in[8],  (const float*)d_in[9],
                  Wt1, (const float*)d_in[11], (const float*)d_in[12], (const float*)d_in[13],
                  n1, n0,      (n1 + 31) / 32};
    TypeParams p2{(const float*)d_in[14], (const float*)d_in[15], (const float*)d_in[16],
                  Wt2, (const float*)d_in[18], (const float*)d_in[19], (const float*)d_in[20],
                  n2, n0 + n1, (n2 + 31) / 32};

    const int nb = p0.nb + p1.nb + p2.nb;
    const int lds_size = 32 * 128 * 2 + 32 * 4 * sizeof(float2);  // 9216 B (max KP=128)
    embed_all<<<nb, 256, lds_size, stream>>>(p0, p1, p2, inv, out);
}